// Round 1
// baseline (480.161 us; speedup 1.0000x reference)
//
#include <hip/hip_runtime.h>
#include <math.h>

#define T_DIM 64
#define C_DIM 256
#define H_DIM 56
#define W_DIM 56
#define HW    (H_DIM * W_DIM)        // 3136
#define CHW   (C_DIM * HW)
#define HALF_C 64

// ---------------------------------------------------------------------------
// Kernel 1: compute g_l[t,h,w], g_r[t,h,w] = tanh(conv3d + bias)
// grid = (7 h-tiles, 64 t), block = 256 threads
// thread: w = tid & 63 (active < 56), ys = tid >> 6 -> output rows h0+2ys, h0+2ys+1
// ---------------------------------------------------------------------------
__global__ __launch_bounds__(256) void gate_kernel(
    const float* __restrict__ x,
    const float* __restrict__ w_l,
    const float* __restrict__ b_l,
    const float* __restrict__ w_r,
    const float* __restrict__ b_r,
    float* __restrict__ g)           // g_l at [0], g_r at [T_DIM*HW]
{
    __shared__ float sx[4][3][10][60];   // [c-sub][dt][row h0-1..h0+8][col w-1..w+56]

    const int t   = blockIdx.y;
    const int h0  = blockIdx.x * 8;
    const int tid = threadIdx.x;
    const int w   = tid & 63;
    const int ys  = tid >> 6;            // 0..3
    const int ha  = h0 + 2 * ys;         // first of two output rows

    float accL0 = 0.f, accL1 = 0.f, accR0 = 0.f, accR1 = 0.f;

    for (int cb = 0; cb < 2 * HALF_C; cb += 4) {
        __syncthreads();
        // stage 4 channels x 3 t-planes x 10 rows x 58 cols
        for (int li = tid; li < 4 * 3 * 10 * 58; li += 256) {
            int col = li % 58;
            int rem = li / 58;
            int row = rem % 10;
            rem /= 10;
            int dt = rem % 3;
            int cc = rem / 3;
            int ts   = (t + dt + (T_DIM - 1)) & (T_DIM - 1);  // t + dt - 1 (cyclic)
            int hs   = h0 + row - 1;
            int wsrc = col - 1;
            float v = 0.f;
            if (hs >= 0 && hs < H_DIM && wsrc >= 0 && wsrc < W_DIM)
                v = x[(size_t)ts * CHW + (size_t)(cb + cc) * HW + hs * W_DIM + wsrc];
            sx[cc][dt][row][col] = v;
        }
        __syncthreads();

        if (w < W_DIM) {
            #pragma unroll
            for (int cc = 0; cc < 4; ++cc) {
                const int cg = cb + cc;
                const float* wp = (cg < HALF_C) ? (w_l + cg * 27)
                                                : (w_r + (cg - HALF_C) * 27);
                float wreg[27];
                #pragma unroll
                for (int k = 0; k < 27; ++k) wreg[k] = wp[k];

                float a0 = 0.f, a1 = 0.f;
                #pragma unroll
                for (int dt = 0; dt < 3; ++dt) {
                    float v0 = sx[cc][dt][2*ys+0][w+0], v1 = sx[cc][dt][2*ys+0][w+1], v2 = sx[cc][dt][2*ys+0][w+2];
                    float u0 = sx[cc][dt][2*ys+1][w+0], u1 = sx[cc][dt][2*ys+1][w+1], u2 = sx[cc][dt][2*ys+1][w+2];
                    float p0 = sx[cc][dt][2*ys+2][w+0], p1 = sx[cc][dt][2*ys+2][w+1], p2 = sx[cc][dt][2*ys+2][w+2];
                    float q0 = sx[cc][dt][2*ys+3][w+0], q1 = sx[cc][dt][2*ys+3][w+1], q2 = sx[cc][dt][2*ys+3][w+2];
                    const float* wd = wreg + dt * 9;
                    a0 += wd[0]*v0 + wd[1]*v1 + wd[2]*v2
                        + wd[3]*u0 + wd[4]*u1 + wd[5]*u2
                        + wd[6]*p0 + wd[7]*p1 + wd[8]*p2;
                    a1 += wd[0]*u0 + wd[1]*u1 + wd[2]*u2
                        + wd[3]*p0 + wd[4]*p1 + wd[5]*p2
                        + wd[6]*q0 + wd[7]*q1 + wd[8]*q2;
                }
                if (cg < HALF_C) { accL0 += a0; accL1 += a1; }
                else             { accR0 += a0; accR1 += a1; }
            }
        }
    }

    if (w < W_DIM) {
        const float bl = b_l[0], br = b_r[0];
        float* gl = g;
        float* gr = g + (size_t)T_DIM * HW;
        const int base = t * HW + ha * W_DIM + w;
        gl[base]         = tanhf(accL0 + bl);
        gl[base + W_DIM] = tanhf(accL1 + bl);
        gr[base]         = tanhf(accR0 + br);
        gr[base + W_DIM] = tanhf(accR1 + br);
    }
}

// ---------------------------------------------------------------------------
// Kernel 2: elementwise combine, float4 per thread
// out[t,c]      = x[t,c] - g_l[t]*x[t,c] + g_l[t+1]*x[t+1,c]   (c < 64)
// out[t,c]      = x[t,c] - g_r[t]*x[t,c] + g_r[t-1]*x[t-1,c]   (64 <= c < 128)
// out[t,c]      = x[t,c]                                        (c >= 128)
// ---------------------------------------------------------------------------
__global__ __launch_bounds__(256) void combine_kernel(
    const float* __restrict__ x,
    const float* __restrict__ g,
    float* __restrict__ out)
{
    const int W4   = W_DIM / 4;   // 14
    const int idx4 = blockIdx.x * 256 + threadIdx.x;

    int w4  = idx4 % W4;
    int rem = idx4 / W4;
    int h   = rem % H_DIM;
    rem    /= H_DIM;
    int c   = rem % C_DIM;
    int t   = rem / C_DIM;

    const float4* x4 = (const float4*)x;
    float4*       o4 = (float4*)out;

    float4 xv = x4[idx4];
    float4 r;

    if (c < HALF_C) {
        int tp = (t + 1) & (T_DIM - 1);
        const float4* gl4 = (const float4*)g;
        float4 g0 = gl4[(t  * H_DIM + h) * W4 + w4];
        float4 g1 = gl4[(tp * H_DIM + h) * W4 + w4];
        float4 xn = x4[((size_t)(tp * C_DIM + c) * H_DIM + h) * W4 + w4];
        r.x = xv.x - g0.x * xv.x + g1.x * xn.x;
        r.y = xv.y - g0.y * xv.y + g1.y * xn.y;
        r.z = xv.z - g0.z * xv.z + g1.z * xn.z;
        r.w = xv.w - g0.w * xv.w + g1.w * xn.w;
    } else if (c < 2 * HALF_C) {
        int tm = (t + T_DIM - 1) & (T_DIM - 1);
        const float4* gr4 = (const float4*)(g + (size_t)T_DIM * HW);
        float4 g0 = gr4[(t  * H_DIM + h) * W4 + w4];
        float4 g1 = gr4[(tm * H_DIM + h) * W4 + w4];
        float4 xn = x4[((size_t)(tm * C_DIM + c) * H_DIM + h) * W4 + w4];
        r.x = xv.x - g0.x * xv.x + g1.x * xn.x;
        r.y = xv.y - g0.y * xv.y + g1.y * xn.y;
        r.z = xv.z - g0.z * xv.z + g1.z * xn.z;
        r.w = xv.w - g0.w * xv.w + g1.w * xn.w;
    } else {
        r = xv;
    }
    o4[idx4] = r;
}

extern "C" void kernel_launch(void* const* d_in, const int* in_sizes, int n_in,
                              void* d_out, int out_size, void* d_ws, size_t ws_size,
                              hipStream_t stream) {
    const float* x   = (const float*)d_in[0];
    const float* w_l = (const float*)d_in[1];
    const float* b_l = (const float*)d_in[2];
    const float* w_r = (const float*)d_in[3];
    const float* b_r = (const float*)d_in[4];
    float* out = (float*)d_out;
    float* g   = (float*)d_ws;   // 2 * 64 * 3136 floats = 1.6 MB

    dim3 grid1(7, 64);           // 7 h-tiles of 8 rows, 64 t
    gate_kernel<<<grid1, 256, 0, stream>>>(x, w_l, b_l, w_r, b_r, g);

    const int n4 = T_DIM * C_DIM * HW / 4;   // 12,845,056
    combine_kernel<<<n4 / 256, 256, 0, stream>>>(x, g, out);
}

// Round 2
// 273.156 us; speedup vs baseline: 1.7578x; 1.7578x over previous
//
#include <hip/hip_runtime.h>
#include <math.h>

#define T_DIM 64
#define C_DIM 256
#define H_DIM 56
#define W_DIM 56
#define HW    (H_DIM * W_DIM)        // 3136
#define CHW   (C_DIM * HW)
#define HALF_C 64
#define THW   (T_DIM * HW)           // 200704

// ---------------------------------------------------------------------------
// Kernel 1: partial conv sums. grid = (7 h-tiles, 64 t, 4 channel-groups)
// z: side = z&1 (0=left,1=right), half = z>>1 (channel offset 32*half)
// Each block: 8 output rows x 56 cols, partial sum over 32 channels.
// Writes pbuf[z][t*HW + h*W + w].
// ---------------------------------------------------------------------------
__global__ __launch_bounds__(256) void gate_kernel(
    const float* __restrict__ x,
    const float* __restrict__ w_l,
    const float* __restrict__ w_r,
    float* __restrict__ pbuf)
{
    __shared__ float sx[4][3][10][64];   // 30 KB

    const int t    = blockIdx.y;
    const int h0   = blockIdx.x * 8;
    const int z    = blockIdx.z;
    const int side = z & 1;
    const int c0   = side * HALF_C + (z >> 1) * 32;
    const int tid  = threadIdx.x;
    const int w    = tid & 63;
    const int reng = tid >> 6;           // 0..3

    const float* wbase = (side ? w_r : w_l) + (z >> 1) * 32 * 27;

    const int tm1 = (t + T_DIM - 1) & (T_DIM - 1);
    const int tp1 = (t + 1) & (T_DIM - 1);
    const size_t baseT0 = (size_t)tm1 * CHW;
    const size_t baseT1 = (size_t)t   * CHW;
    const size_t baseT2 = (size_t)tp1 * CHW;

    float acc0 = 0.f, acc1 = 0.f;

    for (int cb = 0; cb < 32; cb += 4) {
        __syncthreads();
        #pragma unroll
        for (int cc = 0; cc < 4; ++cc) {
            const float* src = x + (size_t)(c0 + cb + cc) * HW;
            #pragma unroll
            for (int dt = 0; dt < 3; ++dt) {
                const float* sp = src + (dt == 0 ? baseT0 : (dt == 1 ? baseT1 : baseT2));
                #pragma unroll
                for (int rp = 0; rp < 3; ++rp) {
                    const int row = rp * 4 + reng;
                    if (rp < 2 || reng < 2) {           // rows 0..9
                        const int hs   = h0 + row - 1;
                        const int wsrc = w - 1;
                        float v = 0.f;
                        if (hs >= 0 && hs < H_DIM && (unsigned)wsrc < W_DIM)
                            v = sp[hs * W_DIM + wsrc];
                        sx[cc][dt][row][w] = v;
                    }
                }
            }
        }
        __syncthreads();

        if (w < W_DIM) {
            #pragma unroll
            for (int cc = 0; cc < 4; ++cc) {
                const float* wp = wbase + (cb + cc) * 27;
                float wreg[27];
                #pragma unroll
                for (int k = 0; k < 27; ++k) wreg[k] = wp[k];

                #pragma unroll
                for (int dt = 0; dt < 3; ++dt) {
                    float v0 = sx[cc][dt][2*reng+0][w+0], v1 = sx[cc][dt][2*reng+0][w+1], v2 = sx[cc][dt][2*reng+0][w+2];
                    float u0 = sx[cc][dt][2*reng+1][w+0], u1 = sx[cc][dt][2*reng+1][w+1], u2 = sx[cc][dt][2*reng+1][w+2];
                    float p0 = sx[cc][dt][2*reng+2][w+0], p1 = sx[cc][dt][2*reng+2][w+1], p2 = sx[cc][dt][2*reng+2][w+2];
                    float q0 = sx[cc][dt][2*reng+3][w+0], q1 = sx[cc][dt][2*reng+3][w+1], q2 = sx[cc][dt][2*reng+3][w+2];
                    const float* wd = wreg + dt * 9;
                    acc0 += wd[0]*v0 + wd[1]*v1 + wd[2]*v2
                          + wd[3]*u0 + wd[4]*u1 + wd[5]*u2
                          + wd[6]*p0 + wd[7]*p1 + wd[8]*p2;
                    acc1 += wd[0]*u0 + wd[1]*u1 + wd[2]*u2
                          + wd[3]*p0 + wd[4]*p1 + wd[5]*p2
                          + wd[6]*q0 + wd[7]*q1 + wd[8]*q2;
                }
            }
        }
    }

    if (w < W_DIM) {
        float* p = pbuf + (size_t)z * THW + t * HW + (h0 + 2 * reng) * W_DIM + w;
        p[0]     = acc0;
        p[W_DIM] = acc1;
    }
}

// ---------------------------------------------------------------------------
// Kernel 2: reduce partials + bias + tanh, in place.
// g_l -> pbuf[0..THW), g_r -> pbuf[THW..2*THW)
// ---------------------------------------------------------------------------
__global__ __launch_bounds__(256) void reduce_tanh_kernel(
    float* __restrict__ pbuf,
    const float* __restrict__ b_l,
    const float* __restrict__ b_r)
{
    const int i = blockIdx.x * 256 + threadIdx.x;
    if (i < THW) {
        const float gl = tanhf(pbuf[i]        + pbuf[2 * THW + i] + b_l[0]);
        const float gr = tanhf(pbuf[THW + i]  + pbuf[3 * THW + i] + b_r[0]);
        pbuf[i]       = gl;
        pbuf[THW + i] = gr;
    }
}

// ---------------------------------------------------------------------------
// Kernel 3: elementwise combine, float4 per thread
// ---------------------------------------------------------------------------
__global__ __launch_bounds__(256) void combine_kernel(
    const float* __restrict__ x,
    const float* __restrict__ g,
    float* __restrict__ out)
{
    const int W4   = W_DIM / 4;   // 14
    const int idx4 = blockIdx.x * 256 + threadIdx.x;

    int w4  = idx4 % W4;
    int rem = idx4 / W4;
    int h   = rem % H_DIM;
    rem    /= H_DIM;
    int c   = rem % C_DIM;
    int t   = rem / C_DIM;

    const float4* x4 = (const float4*)x;
    float4*       o4 = (float4*)out;

    float4 xv = x4[idx4];
    float4 r;

    if (c < HALF_C) {
        int tp = (t + 1) & (T_DIM - 1);
        const float4* gl4 = (const float4*)g;
        float4 g0 = gl4[(t  * H_DIM + h) * W4 + w4];
        float4 g1 = gl4[(tp * H_DIM + h) * W4 + w4];
        float4 xn = x4[((size_t)(tp * C_DIM + c) * H_DIM + h) * W4 + w4];
        r.x = xv.x - g0.x * xv.x + g1.x * xn.x;
        r.y = xv.y - g0.y * xv.y + g1.y * xn.y;
        r.z = xv.z - g0.z * xv.z + g1.z * xn.z;
        r.w = xv.w - g0.w * xv.w + g1.w * xn.w;
    } else if (c < 2 * HALF_C) {
        int tm = (t + T_DIM - 1) & (T_DIM - 1);
        const float4* gr4 = (const float4*)(g + THW);
        float4 g0 = gr4[(t  * H_DIM + h) * W4 + w4];
        float4 g1 = gr4[(tm * H_DIM + h) * W4 + w4];
        float4 xn = x4[((size_t)(tm * C_DIM + c) * H_DIM + h) * W4 + w4];
        r.x = xv.x - g0.x * xv.x + g1.x * xn.x;
        r.y = xv.y - g0.y * xv.y + g1.y * xn.y;
        r.z = xv.z - g0.z * xv.z + g1.z * xn.z;
        r.w = xv.w - g0.w * xv.w + g1.w * xn.w;
    } else {
        r = xv;
    }
    o4[idx4] = r;
}

extern "C" void kernel_launch(void* const* d_in, const int* in_sizes, int n_in,
                              void* d_out, int out_size, void* d_ws, size_t ws_size,
                              hipStream_t stream) {
    const float* x   = (const float*)d_in[0];
    const float* w_l = (const float*)d_in[1];
    const float* b_l = (const float*)d_in[2];
    const float* w_r = (const float*)d_in[3];
    const float* b_r = (const float*)d_in[4];
    float* out  = (float*)d_out;
    float* pbuf = (float*)d_ws;   // 4 * THW floats = 3.2 MB

    dim3 grid1(7, 64, 4);
    gate_kernel<<<grid1, 256, 0, stream>>>(x, w_l, w_r, pbuf);

    reduce_tanh_kernel<<<(THW + 255) / 256, 256, 0, stream>>>(pbuf, b_l, b_r);

    const int n4 = T_DIM * C_DIM * HW / 4;   // 12,845,056
    combine_kernel<<<n4 / 256, 256, 0, stream>>>(x, pbuf, out);
}

// Round 3
// 162.939 us; speedup vs baseline: 2.9469x; 1.6764x over previous
//
#include <hip/hip_runtime.h>
#include <math.h>

#define T_DIM 64
#define C_DIM 256
#define H_DIM 56
#define W_DIM 56
#define HW    (H_DIM * W_DIM)        // 3136
#define CHW   (C_DIM * HW)
#define THW   (T_DIM * HW)           // 200704

// ---------------------------------------------------------------------------
// Gate kernel, register-blocked, no LDS.
// One wave = (side, channel-group g, h-half hh, t). Lane (rg 0..3, wg 0..13):
// output patch rows r0..r0+6 (r0 = 28*hh + 7*rg), cols w0..w0+3 (w0 = 4*wg).
// Loops CPG=64/S channels; per (ch,dt) reads 9 source rows x 6 floats from
// global (L1/L2-hot), 252 FMAs with wave-uniform (SGPR) weights.
// Writes partial-sum plane pbuf[side*S+g][t*HW + ...].
// ---------------------------------------------------------------------------
template<int S>
__global__ __launch_bounds__(256) void gate_kernel(
    const float* __restrict__ x,
    const float* __restrict__ w_l,
    const float* __restrict__ w_r,
    float* __restrict__ pbuf)
{
    constexpr int CPG = 64 / S;

    const int waveid = __builtin_amdgcn_readfirstlane((int)(threadIdx.x >> 6));
    const int unit = blockIdx.x * 4 + waveid;   // ((side*S+g)*2+hh)*64 + t
    const int t    = unit & 63;
    const int hh   = (unit >> 6) & 1;
    const int g    = (unit >> 7) & (S - 1);
    const int side = (unit >> 7) / S;

    const int lane = threadIdx.x & 63;
    const int wg   = lane & 15;          // 0..15, active < 14
    const int rg   = lane >> 4;          // 0..3
    const bool act = (wg < 14);
    const int w0   = act ? wg * 4 : 52;  // clamped for inactive lanes
    const int r0   = hh * 28 + rg * 7;

    const bool have_l = (wg > 0);
    const bool have_r = (w0 + 4) < W_DIM;      // false for wg==13 and inactive
    const int  off0   = have_l ? -1 : 0;
    const int  off5   = have_r ?  4 : 0;

    const float* wtab = (side ? w_r : w_l) + g * CPG * 27;

    const int tm = (t + 63) & 63, tp = (t + 1) & 63;
    const float* tbase[3] = { x + (size_t)tm * CHW,
                              x + (size_t)t  * CHW,
                              x + (size_t)tp * CHW };

    float acc[7][4];
    #pragma unroll
    for (int j = 0; j < 7; ++j)
        #pragma unroll
        for (int k = 0; k < 4; ++k) acc[j][k] = 0.f;

    const int c0 = side * 64 + g * CPG;

    for (int ci = 0; ci < CPG; ++ci) {
        float wgt[27];
        #pragma unroll
        for (int k = 0; k < 27; ++k) wgt[k] = wtab[ci * 27 + k];

        #pragma unroll
        for (int dt = 0; dt < 3; ++dt) {
            const float* plane = tbase[dt] + (size_t)(c0 + ci) * HW;

            #pragma unroll
            for (int s9 = 0; s9 < 9; ++s9) {
                const int sr = r0 - 1 + s9;
                // rows 1..7 always in [0,56); only s9==0 (rg==0,hh==0) and
                // s9==8 (rg==3,hh==1) can fall outside
                bool rv = true;
                int  srow = sr;
                if (s9 == 0)      { rv = (sr >= 0);     srow = rv ? sr : 0; }
                else if (s9 == 8) { rv = (sr < H_DIM);  srow = rv ? sr : (H_DIM - 1); }

                const float* row = plane + srow * W_DIM;
                float  t0 = row[w0 + off0];
                float4 m  = *(const float4*)(row + w0);
                float  t5 = row[w0 + off5];

                float f[6];
                f[0] = have_l ? t0 : 0.f;
                f[1] = m.x; f[2] = m.y; f[3] = m.z; f[4] = m.w;
                f[5] = have_r ? t5 : 0.f;
                if ((s9 == 0 || s9 == 8) && !rv) {
                    f[0] = 0.f; f[1] = 0.f; f[2] = 0.f;
                    f[3] = 0.f; f[4] = 0.f; f[5] = 0.f;
                }

                const int jlo = (s9 >= 2) ? s9 - 2 : 0;
                const int jhi = (s9 <= 6) ? s9 : 6;
                #pragma unroll
                for (int j = jlo; j <= jhi; ++j) {
                    const int dh = s9 - j;          // 0..2
                    const float w0t = wgt[dt * 9 + dh * 3 + 0];
                    const float w1t = wgt[dt * 9 + dh * 3 + 1];
                    const float w2t = wgt[dt * 9 + dh * 3 + 2];
                    #pragma unroll
                    for (int k = 0; k < 4; ++k)
                        acc[j][k] += w0t * f[k] + w1t * f[k + 1] + w2t * f[k + 2];
                }
            }
        }
    }

    if (act) {
        float* pp = pbuf + (size_t)(side * S + g) * THW
                         + (size_t)t * HW + r0 * W_DIM + w0;
        #pragma unroll
        for (int j = 0; j < 7; ++j) {
            float4 v; v.x = acc[j][0]; v.y = acc[j][1]; v.z = acc[j][2]; v.w = acc[j][3];
            *(float4*)(pp + j * W_DIM) = v;
        }
    }
}

// ---------------------------------------------------------------------------
// Reduce partials + bias + tanh.  gl -> slot 0, gr -> slot S.
// ---------------------------------------------------------------------------
template<int S>
__global__ __launch_bounds__(256) void reduce_tanh_kernel(
    float* __restrict__ pbuf,
    const float* __restrict__ b_l,
    const float* __restrict__ b_r)
{
    const int i4 = blockIdx.x * 256 + threadIdx.x;
    if (i4 < THW / 4) {
        float4* p4 = (float4*)pbuf;
        float4 a = {0.f, 0.f, 0.f, 0.f}, b = {0.f, 0.f, 0.f, 0.f};
        #pragma unroll
        for (int g = 0; g < S; ++g) {
            float4 va = p4[(size_t)g * (THW / 4) + i4];
            float4 vb = p4[(size_t)(S + g) * (THW / 4) + i4];
            a.x += va.x; a.y += va.y; a.z += va.z; a.w += va.w;
            b.x += vb.x; b.y += vb.y; b.z += vb.z; b.w += vb.w;
        }
        const float bl = b_l[0], br = b_r[0];
        float4 gl, gr;
        gl.x = tanhf(a.x + bl); gl.y = tanhf(a.y + bl);
        gl.z = tanhf(a.z + bl); gl.w = tanhf(a.w + bl);
        gr.x = tanhf(b.x + br); gr.y = tanhf(b.y + br);
        gr.z = tanhf(b.z + br); gr.w = tanhf(b.w + br);
        p4[i4] = gl;
        p4[(size_t)S * (THW / 4) + i4] = gr;
    }
}

// ---------------------------------------------------------------------------
// Elementwise combine, float4 per thread. gl at g[0], gr at g[groff].
// ---------------------------------------------------------------------------
__global__ __launch_bounds__(256) void combine_kernel(
    const float* __restrict__ x,
    const float* __restrict__ g,
    float* __restrict__ out,
    int groff)
{
    const int W4   = W_DIM / 4;   // 14
    const int idx4 = blockIdx.x * 256 + threadIdx.x;

    int w4  = idx4 % W4;
    int rem = idx4 / W4;
    int h   = rem % H_DIM;
    rem    /= H_DIM;
    int c   = rem % C_DIM;
    int t   = rem / C_DIM;

    const float4* x4 = (const float4*)x;
    float4*       o4 = (float4*)out;

    float4 xv = x4[idx4];
    float4 r;

    if (c < 64) {
        int tp = (t + 1) & (T_DIM - 1);
        const float4* gl4 = (const float4*)g;
        float4 g0 = gl4[(t  * H_DIM + h) * W4 + w4];
        float4 g1 = gl4[(tp * H_DIM + h) * W4 + w4];
        float4 xn = x4[((size_t)(tp * C_DIM + c) * H_DIM + h) * W4 + w4];
        r.x = xv.x - g0.x * xv.x + g1.x * xn.x;
        r.y = xv.y - g0.y * xv.y + g1.y * xn.y;
        r.z = xv.z - g0.z * xv.z + g1.z * xn.z;
        r.w = xv.w - g0.w * xv.w + g1.w * xn.w;
    } else if (c < 128) {
        int tm = (t + T_DIM - 1) & (T_DIM - 1);
        const float4* gr4 = (const float4*)(g + (size_t)groff);
        float4 g0 = gr4[(t  * H_DIM + h) * W4 + w4];
        float4 g1 = gr4[(tm * H_DIM + h) * W4 + w4];
        float4 xn = x4[((size_t)(tm * C_DIM + c) * H_DIM + h) * W4 + w4];
        r.x = xv.x - g0.x * xv.x + g1.x * xn.x;
        r.y = xv.y - g0.y * xv.y + g1.y * xn.y;
        r.z = xv.z - g0.z * xv.z + g1.z * xn.z;
        r.w = xv.w - g0.w * xv.w + g1.w * xn.w;
    } else {
        r = xv;
    }
    o4[idx4] = r;
}

template<int S>
static void launch_all(const float* x, const float* w_l, const float* b_l,
                       const float* w_r, const float* b_r,
                       float* out, float* pbuf, hipStream_t stream)
{
    // units = 2 sides * S groups * 2 halves * 64 t = 256*S ; 4 waves/block
    gate_kernel<S><<<64 * S, 256, 0, stream>>>(x, w_l, w_r, pbuf);
    reduce_tanh_kernel<S><<<(THW / 4 + 255) / 256, 256, 0, stream>>>(pbuf, b_l, b_r);
    const int n4 = T_DIM * C_DIM * HW / 4;
    combine_kernel<<<n4 / 256, 256, 0, stream>>>(x, pbuf, out, S * THW);
}

extern "C" void kernel_launch(void* const* d_in, const int* in_sizes, int n_in,
                              void* d_out, int out_size, void* d_ws, size_t ws_size,
                              hipStream_t stream) {
    const float* x   = (const float*)d_in[0];
    const float* w_l = (const float*)d_in[1];
    const float* b_l = (const float*)d_in[2];
    const float* w_r = (const float*)d_in[3];
    const float* b_r = (const float*)d_in[4];
    float* out  = (float*)d_out;
    float* pbuf = (float*)d_ws;

    const size_t plane_bytes = (size_t)THW * 4;
    if (ws_size >= 32 * plane_bytes)
        launch_all<16>(x, w_l, b_l, w_r, b_r, out, pbuf, stream);
    else if (ws_size >= 16 * plane_bytes)
        launch_all<8>(x, w_l, b_l, w_r, b_r, out, pbuf, stream);
    else
        launch_all<4>(x, w_l, b_l, w_r, b_r, out, pbuf, stream);
}